// Round 19
// baseline (79.450 us; speedup 1.0000x reference)
//
#include <hip/hip_runtime.h>
#include <math.h>

typedef __bf16 bf16x8 __attribute__((ext_vector_type(8)));
typedef __bf16 bf16x4 __attribute__((ext_vector_type(4)));
typedef float  f32x4  __attribute__((ext_vector_type(4)));

#define NT2 12    // partial slots per row (64 cols each)

__device__ inline float gelu_f(float x) {
    return 0.5f * x * (1.0f + erff(x * 0.70710678118654752f));
}

// global -> LDS direct copy, 16 B per lane (HW: wave-uniform LDS base + lane*16)
typedef const __attribute__((address_space(1))) void* gas_t;
typedef __attribute__((address_space(3))) void*       las_t;
__device__ __forceinline__ void gl_lds16(const void* g, void* l) {
    __builtin_amdgcn_global_load_lds((gas_t)g, (las_t)l, 16, 0, 0);
}

// ---------------------------------------------------------------------------
// S0W: W1 (fp32 [K][N]) -> transposed bf16 (RTN): W1t[n*K + k].
// ---------------------------------------------------------------------------
__global__ __launch_bounds__(256) void s0_w1t(
    const float* __restrict__ W1, __bf16* __restrict__ Wt, int Dn)
{
    __shared__ float tile[32][33];
    const int k0 = blockIdx.x * 32;
    const int n0 = blockIdx.y * 32;
    const int tx = threadIdx.x & 31, ty = threadIdx.x >> 5;
    #pragma unroll
    for (int p = 0; p < 4; ++p)
        tile[ty + p * 8][tx] = W1[(size_t)(k0 + ty + p * 8) * Dn + n0 + tx];
    __syncthreads();
    #pragma unroll
    for (int p = 0; p < 4; ++p) {
        const int n = n0 + ty + p * 8, k = k0 + tx;
        Wt[(size_t)n * Dn + k] = (__bf16)tile[tx][ty + p * 8];
    }
}

// ---------------------------------------------------------------------------
// K1: FULL-ROW blocks — BM=64, BN=768 (all columns). A (fp32 X) is read
// EXACTLY ONCE (50 MB, HBM floor); B working set = whole W1t (1.18 MB)
// streamed per k-step by every block -> L2-resident per XCD after first
// iter (traffic becomes L2-hits, not L3). Grid 256 blocks = 1/CU
// (LDS 104 KB). 8 waves = 2 row-bands x 4 wc; wave owns slots {wc,wc+4,wc+8}
// (64-col slots) -> acc[3][2][4]. Per-slot math identical to prior rounds ->
// logits bit-identical (absmax checksum 7.039062).
//   A: reg-staged fp32 -> cvt bf16 -> ds_write_b64 (granule-XOR swizzle)
//   B: gl_lds direct, 6 chunks/thread, chunk-XOR swizzle (proven layout)
// ---------------------------------------------------------------------------
__global__ __launch_bounds__(512) void k1_row(
    const float* __restrict__ X, const __bf16* __restrict__ W1t,
    const float* __restrict__ b1, const float* __restrict__ W2,
    float* __restrict__ partial, int Kd)
{
    __shared__ __bf16 Ash[2][64 * 32];     //  4 KB per buffer
    __shared__ __bf16 Bsh[2][768 * 32];    // 48 KB per buffer

    const int t    = threadIdx.x;
    const int lane = t & 63;
    const int w    = t >> 6;          // 0..7
    const int wr   = w >> 2;          // 0..1: 32-row band
    const int wc   = w & 3;           // 0..3: slot group
    const int ln15 = lane & 15, lg = lane >> 4;
    const int m0   = blockIdx.x * 64;

    // ---- A staging: row ar = t>>3, granule ag = t&7 (4 fp32 -> 4 bf16) ----
    const int ar = t >> 3, ag = t & 7;
    const float* gA = X + (size_t)(m0 + ar) * Kd + ag * 4;
    // granule-position swizzle p = g ^ (2*((ar>>1)&3)) keeps b128 reads 2-way
    const int awr = ar * 32 + (ag ^ ((((ar >> 1) & 3)) << 1)) * 4;  // elems

    // ---- B staging: 6 chunks/thread; chunk c_i = t + 512*i ----
    const int br  = t >> 2;                       // base row 0..127
    const int bkw = (t & 3) ^ ((br >> 1) & 3);    // same kw for all i
    const __bf16* gBbase = W1t + (size_t)br * Kd + bkw * 8;

    // ---- fragment LDS offsets (constant across k-loop) ----
    int aoff[2], boff[3][4];
    #pragma unroll
    for (int mf = 0; mf < 2; ++mf) {
        const int r = wr * 32 + mf * 16 + ln15;
        aoff[mf] = r * 32 + (lg ^ ((r >> 1) & 3)) * 8;
    }
    #pragma unroll
    for (int rep = 0; rep < 3; ++rep)
        #pragma unroll
        for (int nf = 0; nf < 4; ++nf) {
            const int rb = (wc + 4 * rep) * 64 + nf * 16 + ln15;  // 0..767
            boff[rep][nf] = rb * 32 + (lg ^ ((rb >> 1) & 3)) * 8;
        }

    f32x4 acc[3][2][4];
    #pragma unroll
    for (int rep = 0; rep < 3; ++rep)
        #pragma unroll
        for (int i = 0; i < 2; ++i)
            #pragma unroll
            for (int j = 0; j < 4; ++j)
                acc[rep][i][j] = (f32x4){0.f, 0.f, 0.f, 0.f};

    // ---- prologue: stage tile 0 into buf 0 ----
    {
        const float4 a4 = *(const float4*)(gA);
        bf16x4 ab;
        ab[0] = (__bf16)a4.x; ab[1] = (__bf16)a4.y;
        ab[2] = (__bf16)a4.z; ab[3] = (__bf16)a4.w;
        *(bf16x4*)&Ash[0][awr] = ab;
        #pragma unroll
        for (int i = 0; i < 6; ++i)
            gl_lds16(gBbase + (size_t)128 * i * Kd, &Bsh[0][(t + 512 * i) * 8]);
    }
    __syncthreads();

    const int nt = Kd / 32;   // 24
    int cur = 0;
    for (int kt = 0; kt < nt; ++kt) {
        float4 a4;
        const bool more = (kt + 1 < nt);
        if (more) {
            const int ko = (kt + 1) * 32;
            a4 = *(const float4*)(gA + ko);        // A(kt+1): fly under MFMA
            #pragma unroll
            for (int i = 0; i < 6; ++i)
                gl_lds16(gBbase + (size_t)128 * i * Kd + ko,
                         &Bsh[cur ^ 1][(t + 512 * i) * 8]);
        }

        // ---- MFMA phase: 2 A-frags, 12 B-frags, 24 MFMA ----
        bf16x8 fa[2];
        #pragma unroll
        for (int mf = 0; mf < 2; ++mf)
            fa[mf] = *(const bf16x8*)&Ash[cur][aoff[mf]];
        #pragma unroll
        for (int rep = 0; rep < 3; ++rep) {
            bf16x8 fb[4];
            #pragma unroll
            for (int nf = 0; nf < 4; ++nf)
                fb[nf] = *(const bf16x8*)&Bsh[cur][boff[rep][nf]];
            #pragma unroll
            for (int mf = 0; mf < 2; ++mf)
                #pragma unroll
                for (int nf = 0; nf < 4; ++nf)
                    acc[rep][mf][nf] = __builtin_amdgcn_mfma_f32_16x16x32_bf16(
                        fa[mf], fb[nf], acc[rep][mf][nf], 0, 0, 0);
        }

        if (more) {
            bf16x4 ab;
            ab[0] = (__bf16)a4.x; ab[1] = (__bf16)a4.y;
            ab[2] = (__bf16)a4.z; ab[3] = (__bf16)a4.w;
            *(bf16x4*)&Ash[cur ^ 1][awr] = ab;
        }
        __syncthreads();   // drains vmcnt (B) + lgkm (A write): next buf ready
        cur ^= 1;
    }

    // ---- epilogue: per-row gelu(c+b1)*W2 sums, one 64-col slot at a time ----
    #pragma unroll
    for (int rep = 0; rep < 3; ++rep) {
        const int slot = wc + 4 * rep;
        float b1v[4], w2v[4];
        #pragma unroll
        for (int nf = 0; nf < 4; ++nf) {
            const int n = slot * 64 + nf * 16 + ln15;
            b1v[nf] = b1[n];
            w2v[nf] = W2[n];
        }
        #pragma unroll
        for (int mf = 0; mf < 2; ++mf)
            #pragma unroll
            for (int j = 0; j < 4; ++j) {
                float s = 0.f;
                #pragma unroll
                for (int nf = 0; nf < 4; ++nf) {
                    float c = acc[rep][mf][nf][j] + b1v[nf];
                    s += gelu_f(c) * w2v[nf];
                }
                s += __shfl_xor(s, 1);
                s += __shfl_xor(s, 2);
                s += __shfl_xor(s, 4);
                s += __shfl_xor(s, 8);
                if (ln15 == 0) {
                    const int m = m0 + wr * 32 + mf * 16 + lg * 4 + j;
                    partial[(size_t)m * NT2 + slot] = s;
                }
            }
    }
}

// ---------------------------------------------------------------------------
// K2a: M-parallel logits + probs. One thread per position; 12 contiguous
// partial loads. 64 blocks -> latency covered by TLP.
// ---------------------------------------------------------------------------
__global__ __launch_bounds__(256) void k2a_logits(
    const float* __restrict__ partial, const float* __restrict__ lengths,
    const float* __restrict__ b2p, float* __restrict__ logits,
    float* __restrict__ out_probs, int S)
{
    const int idx = blockIdx.x * 256 + threadIdx.x;
    const int b = idx / S, s = idx - b * S;
    float sum = b2p[0];
    #pragma unroll
    for (int jt = 0; jt < NT2; ++jt)
        sum += partial[(size_t)idx * NT2 + jt];
    logits[idx] = sum;
    const int len = (int)(lengths[b] * (float)S);
    out_probs[idx] = (s < len) ? 1.0f / (1.0f + expf(-sum)) : 0.0f;
}

// ---------------------------------------------------------------------------
// K2b: per-batch flags (logit>0, last_valid=1); scan -> bpos; nb/short/lens.
// ---------------------------------------------------------------------------
__global__ __launch_bounds__(256) void k2b_scan(
    const float* __restrict__ logits, const float* __restrict__ lengths,
    float* __restrict__ out_short, float* __restrict__ out_nb,
    float* __restrict__ out_lens, int* __restrict__ bpos,
    int* __restrict__ nb_arr, int S, int K)
{
    const int b = blockIdx.x;
    const int t = threadIdx.x;
    const int len = (int)(lengths[b] * (float)S);

    __shared__ int cnt[256];
    __shared__ int flags_s[2048];

    const int RP = S / 256;
    const int base_s = t * RP;
    int local = 0;
    #pragma unroll
    for (int r = 0; r < 8; ++r) {
        int s = base_s + r;
        bool v = (s < len);
        int f = (s == len - 1) ? 1 : ((v && logits[(size_t)b * S + s] > 0.0f) ? 1 : 0);
        flags_s[s] = f;
        local += f;
    }
    cnt[t] = local;
    __syncthreads();
    for (int off = 1; off < 256; off <<= 1) {
        int v = cnt[t];
        int u = (t >= off) ? cnt[t - off] : 0;
        __syncthreads();
        cnt[t] = v + u;
        __syncthreads();
    }
    int excl = cnt[t] - local;
    int total = cnt[255];
    for (int r = 0; r < RP; ++r) {
        int s = base_s + r;
        if (flags_s[s]) { bpos[b * S + excl] = s; ++excl; }
    }
    if (t == 0) {
        nb_arr[b] = total;
        float nbf = (float)total;
        float Kf  = (float)K;
        out_nb[b]   = nbf;
        out_lens[b] = (float)len;
        float sh;
        if (nbf >= Kf - 1.0f)      sh = 1.0f;
        else if (nbf > 0.0f)       sh = (nbf + 1.0f) / Kf;
        else                       sh = 0.0f;
        out_short[b] = sh;
    }
}

// ---------------------------------------------------------------------------
// K3: segment-mean pooling from fp32 X. One block per (b,k).
// ---------------------------------------------------------------------------
__global__ __launch_bounds__(192) void k3_pool(
    const float* __restrict__ X, const int* __restrict__ bpos,
    const int* __restrict__ nb_arr, float* __restrict__ pooled,
    int S, int D, int K)
{
    const int bk = blockIdx.x;
    const int b  = bk / K;
    const int k  = bk - b * K;
    const int t  = threadIdx.x;
    const int nb = nb_arr[b];

    float4 acc = {0.f, 0.f, 0.f, 0.f};
    if (k < nb) {
        int start = (k == 0) ? 0 : (bpos[b * S + k - 1] + 1);
        int end   = bpos[b * S + k] + 1;
        float cntf = (float)(end - start);
        for (int s = start; s < end; ++s) {
            const float4 v = *(const float4*)&X[((size_t)b * S + s) * D + t * 4];
            acc.x += v.x; acc.y += v.y; acc.z += v.z; acc.w += v.w;
        }
        acc.x /= cntf; acc.y /= cntf; acc.z /= cntf; acc.w /= cntf;
    }
    *(float4*)&pooled[((size_t)b * K + k) * D + t * 4] = acc;
}

// ---------------------------------------------------------------------------
extern "C" void kernel_launch(void* const* d_in, const int* in_sizes, int n_in,
                              void* d_out, int out_size, void* d_ws, size_t ws_size,
                              hipStream_t stream) {
    const float* hidden  = (const float*)d_in[0];
    const float* lengths = (const float*)d_in[1];
    const float* W1      = (const float*)d_in[2];
    const float* b1      = (const float*)d_in[3];
    const float* W2      = (const float*)d_in[4];
    const float* b2      = (const float*)d_in[5];

    const int B = in_sizes[1];
    const int D = in_sizes[3];
    const int S = in_sizes[0] / (B * D);
    const int M = B * S;
    const int K = (out_size - B * S - 3 * B) / (B * D);

    float* out_pooled = (float*)d_out;
    float* out_probs  = out_pooled + (size_t)B * K * D;
    float* out_short  = out_probs + (size_t)B * S;
    float* out_nb     = out_short + B;
    float* out_lens   = out_nb + B;

    // d_ws: partial (786 KB) + logits (64 KB) + bpos (64 KB) + nb_arr
    char* wsp = (char*)d_ws;
    float* partial = (float*)wsp; wsp += (size_t)M * NT2 * sizeof(float);
    float* logits  = (float*)wsp; wsp += (size_t)M * sizeof(float);
    int*   bpos    = (int*)wsp;   wsp += (size_t)M * sizeof(int);
    int*   nb_arr  = (int*)wsp;

    // bf16 W1^T lives in the pooled output region (K3 overwrites it at the end).
    __bf16* W1t = (__bf16*)out_pooled;

    dim3 gs(D / 32, D / 32);
    s0_w1t<<<gs, 256, 0, stream>>>(W1, W1t, D);

    k1_row<<<M / 64, 512, 0, stream>>>(hidden, W1t, b1, W2, partial, D);

    k2a_logits<<<M / 256, 256, 0, stream>>>(partial, lengths, b2, logits,
                                            out_probs, S);
    k2b_scan<<<B, 256, 0, stream>>>(logits, lengths, out_short, out_nb,
                                    out_lens, bpos, nb_arr, S, K);
    k3_pool<<<B * K, D / 4, 0, stream>>>(hidden, bpos, nb_arr, out_pooled, S, D, K);
}

// Round 20
// 76.868 us; speedup vs baseline: 1.0336x; 1.0336x over previous
//
#include <hip/hip_runtime.h>
#include <math.h>

typedef __bf16 bf16x8 __attribute__((ext_vector_type(8)));
typedef float  f32x4  __attribute__((ext_vector_type(4)));

#define NT2 12    // partial slots per row = (D/BN=6) * 2 wave-columns

__device__ inline float gelu_f(float x) {
    return 0.5f * x * (1.0f + erff(x * 0.70710678118654752f));
}

// global -> LDS direct copy, 16 B per lane (HW: wave-uniform LDS base + lane*16)
typedef const __attribute__((address_space(1))) void* gas_t;
typedef __attribute__((address_space(3))) void*       las_t;
__device__ __forceinline__ void gl_lds16(const void* g, void* l) {
    __builtin_amdgcn_global_load_lds((gas_t)g, (las_t)l, 16, 0, 0);
}

// ---------------------------------------------------------------------------
// S0W: W1 (fp32 [K][N]) -> transposed bf16 (RTN): W1t[n*K + k].
// ---------------------------------------------------------------------------
__global__ __launch_bounds__(256) void s0_w1t(
    const float* __restrict__ W1, __bf16* __restrict__ Wt, int Dn)
{
    __shared__ float tile[32][33];
    const int k0 = blockIdx.x * 32;
    const int n0 = blockIdx.y * 32;
    const int tx = threadIdx.x & 31, ty = threadIdx.x >> 5;
    #pragma unroll
    for (int p = 0; p < 4; ++p)
        tile[ty + p * 8][tx] = W1[(size_t)(k0 + ty + p * 8) * Dn + n0 + tx];
    __syncthreads();
    #pragma unroll
    for (int p = 0; p < 4; ++p) {
        const int n = n0 + ty + p * 8, k = k0 + tx;
        Wt[(size_t)n * Dn + k] = (__bf16)tile[tx][ty + p * 8];
    }
}

__device__ __forceinline__ bf16x8 cvt8(const float4& lo, const float4& hi) {
    bf16x8 ab;
    ab[0] = (__bf16)lo.x; ab[1] = (__bf16)lo.y;
    ab[2] = (__bf16)lo.z; ab[3] = (__bf16)lo.w;
    ab[4] = (__bf16)hi.x; ab[5] = (__bf16)hi.y;
    ab[6] = (__bf16)hi.z; ab[7] = (__bf16)hi.w;
    return ab;
}

// ---------------------------------------------------------------------------
// K1: BK=64 per barrier — halves latency-exposure windows (24 -> 12) and
// doubles per-window MFMA cover (16 MFMA). 128x128 tile, 8 waves (4x2,
// 32x64 each), 2-phase dbuf (LDS 64 KB -> 2 blocks/CU):
//   A: fp32 reg-staged (16 floats/thread, 4 float4 issued at loop top, fly
//      under MFMA) -> cvt bf16 AFTER MFMA phase -> 2x ds_write_b128.
//   B: gl_lds direct, 2 chunks/thread.
// Row = 8 granules of 8 bf16; 3-bit XOR swizzle s(r)=(r>>1)&7 on write
// source and frag read -> 2-way banks (free). Per-acc K-order unchanged
// (ascending 32-chunks) -> logits bit-identical (absmax checksum 7.039062).
// ---------------------------------------------------------------------------
__global__ __launch_bounds__(512) void k1_bk64(
    const float* __restrict__ X, const __bf16* __restrict__ W1t,
    const float* __restrict__ b1, const float* __restrict__ W2,
    float* __restrict__ partial, int Kd)
{
    __shared__ __bf16 Ash[2][128 * 64];   // 16 KB per buffer
    __shared__ __bf16 Bsh[2][128 * 64];   // 16 KB per buffer

    const int t    = threadIdx.x;
    const int lane = t & 63;
    const int w    = t >> 6;          // 0..7
    const int wr   = w >> 1;          // 0..3: 32-row band
    const int wc   = w & 1;           // 0..1: 64-col band
    const int ln15 = lane & 15, lg = lane >> 4;
    const int m0   = blockIdx.x * 128;
    const int n0   = blockIdx.y * 128;

    // ---- A staging: row ar = t>>2, 16 floats at (t&3)*16 = granules g0,g0+1
    const int ar = t >> 2;
    const int g0 = (t & 3) * 2;
    const int sA = (ar >> 1) & 7;
    const float* gA = X + (size_t)(m0 + ar) * Kd + g0 * 8;
    const int awr0 = ar * 64 + (g0 ^ sA) * 8;          // LDS elems
    const int awr1 = ar * 64 + ((g0 + 1) ^ sA) * 8;

    // ---- B staging: 1024 chunks (16 B); thread stages chunks t and t+512.
    const int br0 = t >> 3,         bg0 = (t & 7) ^ ((br0 >> 1) & 7);
    const int br1 = (t + 512) >> 3, bg1 = ((t + 512) & 7) ^ ((br1 >> 1) & 7);
    const __bf16* gB0 = W1t + (size_t)(n0 + br0) * Kd + bg0 * 8;
    const __bf16* gB1 = W1t + (size_t)(n0 + br1) * Kd + bg1 * 8;

    // ---- fragment LDS offsets: [kk][frag], global granule gg = kk*4+lg ----
    int aoff[2][2], boff[2][4];
    #pragma unroll
    for (int kk = 0; kk < 2; ++kk) {
        #pragma unroll
        for (int mf = 0; mf < 2; ++mf) {
            const int r = wr * 32 + mf * 16 + ln15;
            aoff[kk][mf] = r * 64 + ((kk * 4 + lg) ^ ((r >> 1) & 7)) * 8;
        }
        #pragma unroll
        for (int nf = 0; nf < 4; ++nf) {
            const int r = wc * 64 + nf * 16 + ln15;
            boff[kk][nf] = r * 64 + ((kk * 4 + lg) ^ ((r >> 1) & 7)) * 8;
        }
    }

    f32x4 acc[2][4];
    #pragma unroll
    for (int i = 0; i < 2; ++i)
        #pragma unroll
        for (int j = 0; j < 4; ++j)
            acc[i][j] = (f32x4){0.f, 0.f, 0.f, 0.f};

    // ---- prologue: stage tile 0 into buf 0 ----
    {
        const float4 a0 = *(const float4*)(gA);
        const float4 a1 = *(const float4*)(gA + 4);
        const float4 a2 = *(const float4*)(gA + 8);
        const float4 a3 = *(const float4*)(gA + 12);
        *(bf16x8*)&Ash[0][awr0] = cvt8(a0, a1);
        *(bf16x8*)&Ash[0][awr1] = cvt8(a2, a3);
        gl_lds16(gB0, &Bsh[0][t * 8]);
        gl_lds16(gB1, &Bsh[0][(t + 512) * 8]);
    }
    __syncthreads();

    const int nt = Kd / 64;   // 12
    int cur = 0;
    for (int kt = 0; kt < nt; ++kt) {
        float4 a0, a1, a2, a3;
        const bool more = (kt + 1 < nt);
        if (more) {
            const int ko = (kt + 1) * 64;
            a0 = *(const float4*)(gA + ko);        // fly under MFMA phase
            a1 = *(const float4*)(gA + ko + 4);
            a2 = *(const float4*)(gA + ko + 8);
            a3 = *(const float4*)(gA + ko + 12);
            gl_lds16(gB0 + ko, &Bsh[cur ^ 1][t * 8]);
            gl_lds16(gB1 + ko, &Bsh[cur ^ 1][(t + 512) * 8]);
        }

        // ---- MFMA phase: 2 k-halves x 8 = 16 MFMA ----
        #pragma unroll
        for (int kk = 0; kk < 2; ++kk) {
            bf16x8 fa[2], fb[4];
            #pragma unroll
            for (int mf = 0; mf < 2; ++mf)
                fa[mf] = *(const bf16x8*)&Ash[cur][aoff[kk][mf]];
            #pragma unroll
            for (int nf = 0; nf < 4; ++nf)
                fb[nf] = *(const bf16x8*)&Bsh[cur][boff[kk][nf]];
            #pragma unroll
            for (int mf = 0; mf < 2; ++mf)
                #pragma unroll
                for (int nf = 0; nf < 4; ++nf)
                    acc[mf][nf] = __builtin_amdgcn_mfma_f32_16x16x32_bf16(
                        fa[mf], fb[nf], acc[mf][nf], 0, 0, 0);
        }

        if (more) {
            *(bf16x8*)&Ash[cur ^ 1][awr0] = cvt8(a0, a1);
            *(bf16x8*)&Ash[cur ^ 1][awr1] = cvt8(a2, a3);
        }
        __syncthreads();   // drains vmcnt (B) + lgkm (A write): next buf ready
        cur ^= 1;
    }

    // ---- epilogue: per-row sum of gelu(c + b1)*W2 over this wave's 64 cols ----
    float b1v[4], w2v[4];
    #pragma unroll
    for (int nf = 0; nf < 4; ++nf) {
        const int n = n0 + wc * 64 + nf * 16 + ln15;
        b1v[nf] = b1[n];
        w2v[nf] = W2[n];
    }
    #pragma unroll
    for (int mf = 0; mf < 2; ++mf)
        #pragma unroll
        for (int j = 0; j < 4; ++j) {
            float s = 0.f;
            #pragma unroll
            for (int nf = 0; nf < 4; ++nf) {
                float c = acc[mf][nf][j] + b1v[nf];
                s += gelu_f(c) * w2v[nf];
            }
            s += __shfl_xor(s, 1);
            s += __shfl_xor(s, 2);
            s += __shfl_xor(s, 4);
            s += __shfl_xor(s, 8);
            if (ln15 == 0) {
                const int m = m0 + wr * 32 + mf * 16 + lg * 4 + j;
                partial[(size_t)m * NT2 + blockIdx.y * 2 + wc] = s;
            }
        }
}

// ---------------------------------------------------------------------------
// K2a: M-parallel logits + probs. One thread per position; 12 contiguous
// partial loads. 64 blocks -> latency covered by TLP.
// ---------------------------------------------------------------------------
__global__ __launch_bounds__(256) void k2a_logits(
    const float* __restrict__ partial, const float* __restrict__ lengths,
    const float* __restrict__ b2p, float* __restrict__ logits,
    float* __restrict__ out_probs, int S)
{
    const int idx = blockIdx.x * 256 + threadIdx.x;
    const int b = idx / S, s = idx - b * S;
    float sum = b2p[0];
    #pragma unroll
    for (int jt = 0; jt < NT2; ++jt)
        sum += partial[(size_t)idx * NT2 + jt];
    logits[idx] = sum;
    const int len = (int)(lengths[b] * (float)S);
    out_probs[idx] = (s < len) ? 1.0f / (1.0f + expf(-sum)) : 0.0f;
}

// ---------------------------------------------------------------------------
// K2b: per-batch flags (logit>0, last_valid=1); scan -> bpos; nb/short/lens.
// ---------------------------------------------------------------------------
__global__ __launch_bounds__(256) void k2b_scan(
    const float* __restrict__ logits, const float* __restrict__ lengths,
    float* __restrict__ out_short, float* __restrict__ out_nb,
    float* __restrict__ out_lens, int* __restrict__ bpos,
    int* __restrict__ nb_arr, int S, int K)
{
    const int b = blockIdx.x;
    const int t = threadIdx.x;
    const int len = (int)(lengths[b] * (float)S);

    __shared__ int cnt[256];
    __shared__ int flags_s[2048];

    const int RP = S / 256;
    const int base_s = t * RP;
    int local = 0;
    #pragma unroll
    for (int r = 0; r < 8; ++r) {
        int s = base_s + r;
        bool v = (s < len);
        int f = (s == len - 1) ? 1 : ((v && logits[(size_t)b * S + s] > 0.0f) ? 1 : 0);
        flags_s[s] = f;
        local += f;
    }
    cnt[t] = local;
    __syncthreads();
    for (int off = 1; off < 256; off <<= 1) {
        int v = cnt[t];
        int u = (t >= off) ? cnt[t - off] : 0;
        __syncthreads();
        cnt[t] = v + u;
        __syncthreads();
    }
    int excl = cnt[t] - local;
    int total = cnt[255];
    for (int r = 0; r < RP; ++r) {
        int s = base_s + r;
        if (flags_s[s]) { bpos[b * S + excl] = s; ++excl; }
    }
    if (t == 0) {
        nb_arr[b] = total;
        float nbf = (float)total;
        float Kf  = (float)K;
        out_nb[b]   = nbf;
        out_lens[b] = (float)len;
        float sh;
        if (nbf >= Kf - 1.0f)      sh = 1.0f;
        else if (nbf > 0.0f)       sh = (nbf + 1.0f) / Kf;
        else                       sh = 0.0f;
        out_short[b] = sh;
    }
}

// ---------------------------------------------------------------------------
// K3: segment-mean pooling from fp32 X. One block per (b,k).
// ---------------------------------------------------------------------------
__global__ __launch_bounds__(192) void k3_pool(
    const float* __restrict__ X, const int* __restrict__ bpos,
    const int* __restrict__ nb_arr, float* __restrict__ pooled,
    int S, int D, int K)
{
    const int bk = blockIdx.x;
    const int b  = bk / K;
    const int k  = bk - b * K;
    const int t  = threadIdx.x;
    const int nb = nb_arr[b];

    float4 acc = {0.f, 0.f, 0.f, 0.f};
    if (k < nb) {
        int start = (k == 0) ? 0 : (bpos[b * S + k - 1] + 1);
        int end   = bpos[b * S + k] + 1;
        float cntf = (float)(end - start);
        for (int s = start; s < end; ++s) {
            const float4 v = *(const float4*)&X[((size_t)b * S + s) * D + t * 4];
            acc.x += v.x; acc.y += v.y; acc.z += v.z; acc.w += v.w;
        }
        acc.x /= cntf; acc.y /= cntf; acc.z /= cntf; acc.w /= cntf;
    }
    *(float4*)&pooled[((size_t)b * K + k) * D + t * 4] = acc;
}

// ---------------------------------------------------------------------------
extern "C" void kernel_launch(void* const* d_in, const int* in_sizes, int n_in,
                              void* d_out, int out_size, void* d_ws, size_t ws_size,
                              hipStream_t stream) {
    const float* hidden  = (const float*)d_in[0];
    const float* lengths = (const float*)d_in[1];
    const float* W1      = (const float*)d_in[2];
    const float* b1      = (const float*)d_in[3];
    const float* W2      = (const float*)d_in[4];
    const float* b2      = (const float*)d_in[5];

    const int B = in_sizes[1];
    const int D = in_sizes[3];
    const int S = in_sizes[0] / (B * D);
    const int M = B * S;
    const int K = (out_size - B * S - 3 * B) / (B * D);

    float* out_pooled = (float*)d_out;
    float* out_probs  = out_pooled + (size_t)B * K * D;
    float* out_short  = out_probs + (size_t)B * S;
    float* out_nb     = out_short + B;
    float* out_lens   = out_nb + B;

    // d_ws: partial (786 KB) + logits (64 KB) + bpos (64 KB) + nb_arr
    char* wsp = (char*)d_ws;
    float* partial = (float*)wsp; wsp += (size_t)M * NT2 * sizeof(float);
    float* logits  = (float*)wsp; wsp += (size_t)M * sizeof(float);
    int*   bpos    = (int*)wsp;   wsp += (size_t)M * sizeof(int);
    int*   nb_arr  = (int*)wsp;

    // bf16 W1^T lives in the pooled output region (K3 overwrites it at the end).
    __bf16* W1t = (__bf16*)out_pooled;

    dim3 gs(D / 32, D / 32);
    s0_w1t<<<gs, 256, 0, stream>>>(W1, W1t, D);

    dim3 g1(M / 128, D / 128);
    k1_bk64<<<g1, 512, 0, stream>>>(hidden, W1t, b1, W2, partial, D);

    k2a_logits<<<M / 256, 256, 0, stream>>>(partial, lengths, b2, logits,
                                            out_probs, S);
    k2b_scan<<<B, 256, 0, stream>>>(logits, lengths, out_short, out_nb,
                                    out_lens, bpos, nb_arr, S, K);
    k3_pool<<<B * K, D / 4, 0, stream>>>(hidden, bpos, nb_arr, out_pooled, S, D, K);
}

// Round 21
// 59.110 us; speedup vs baseline: 1.3441x; 1.3004x over previous
//
#include <hip/hip_runtime.h>
#include <math.h>

typedef __bf16 bf16x8 __attribute__((ext_vector_type(8)));
typedef float  f32x4  __attribute__((ext_vector_type(4)));

#define NT2 12    // partial slots per row = (D/BN=6) * 2 wave-columns

__device__ inline float gelu_f(float x) {
    return 0.5f * x * (1.0f + erff(x * 0.70710678118654752f));
}

// global -> LDS direct copy, 16 B per lane (HW: wave-uniform LDS base + lane*16)
typedef const __attribute__((address_space(1))) void* gas_t;
typedef __attribute__((address_space(3))) void*       las_t;
__device__ __forceinline__ void gl_lds16(const void* g, void* l) {
    __builtin_amdgcn_global_load_lds((gas_t)g, (las_t)l, 16, 0, 0);
}

// ---------------------------------------------------------------------------
// S0W: W1 (fp32 [K][N]) -> transposed bf16 (RTN): W1t[n*K + k].
// ---------------------------------------------------------------------------
__global__ __launch_bounds__(256) void s0_w1t(
    const float* __restrict__ W1, __bf16* __restrict__ Wt, int Dn)
{
    __shared__ float tile[32][33];
    const int k0 = blockIdx.x * 32;
    const int n0 = blockIdx.y * 32;
    const int tx = threadIdx.x & 31, ty = threadIdx.x >> 5;
    #pragma unroll
    for (int p = 0; p < 4; ++p)
        tile[ty + p * 8][tx] = W1[(size_t)(k0 + ty + p * 8) * Dn + n0 + tx];
    __syncthreads();
    #pragma unroll
    for (int p = 0; p < 4; ++p) {
        const int n = n0 + ty + p * 8, k = k0 + tx;
        Wt[(size_t)n * Dn + k] = (__bf16)tile[tx][ty + p * 8];
    }
}

// ---------------------------------------------------------------------------
// K1 (best measured: round 14, 44 us; total 59.1 us): bf16 MFMA GEMM reading
// fp32 X directly. 128x128 tile, BK=32, 8 waves (4x2, 32x64 each), 2-phase
// dbuf LDS, hybrid staging (T14):
//   A: reg-staged — load 2xfloat4 of tile kt+1 at loop TOP (flies under
//      MFMA), cvt fp32->bf16 AFTER the MFMA phase, one ds_write_b128.
//   B: global_load_lds direct (8 KB/buf).
// XOR chunk swizzle both sides -> 2-way banks (free). One barrier/iter.
// STRUCTURAL CEILING (rounds 14-20 sweep): ~453 MB tile traffic (A x6 +
// B x128 re-reads) served at 10.3-10.6 TB/s cache rate in every >=3-block/CU
// structure; depth (r17/r18), occupancy (r16/r19), aspect (r16/r19), XCD
// swizzle (r15), BK (r20) all measured equal or worse. Fused gelu epilogue
// (needs full-K sum) forbids K-split, the only remaining traffic cut.
// ---------------------------------------------------------------------------
__global__ __launch_bounds__(512) void k1_hyb(
    const float* __restrict__ X, const __bf16* __restrict__ W1t,
    const float* __restrict__ b1, const float* __restrict__ W2,
    float* __restrict__ partial, int Kd)
{
    __shared__ __bf16 Ash[2][128 * 32];   // bf16 A tile, 8 KB per buffer
    __shared__ __bf16 Bsh[2][128 * 32];   // bf16 B tile, 8 KB per buffer

    const int t    = threadIdx.x;
    const int lane = t & 63;
    const int w    = t >> 6;          // 0..7
    const int wr   = w >> 1;          // 0..3: 32-row band
    const int wc   = w & 1;           // 0..1: 64-col band
    const int ln15 = lane & 15, lg = lane >> 4;
    const int m0   = blockIdx.x * 128;
    const int n0   = blockIdx.y * 128;

    // A staging: thread owns row r = t>>2, bf16 chunk q = t&3 (8 fp32)
    const int ar  = t >> 2, aq = t & 3;
    const int asw = (ar >> 1) & 3;
    const float* gA = X + (size_t)(m0 + ar) * Kd + aq * 8;
    const int    awr = ar * 32 + (aq ^ asw) * 8;    // LDS write offset (elems)

    // B staging: 512 chunks (16 B = 8 bf16); thread stages chunk t.
    const int brow = t >> 2;
    const int bkw  = (t & 3) ^ ((brow >> 1) & 3);
    const __bf16* gB = W1t + (size_t)(n0 + brow) * Kd + bkw * 8;

    // fragment LDS offsets (constant across k-loop)
    int aoff[2], boff[4];
    #pragma unroll
    for (int mf = 0; mf < 2; ++mf) {
        const int r = wr * 32 + mf * 16 + ln15;
        aoff[mf] = r * 32 + (lg ^ ((r >> 1) & 3)) * 8;
    }
    #pragma unroll
    for (int nf = 0; nf < 4; ++nf) {
        const int r = wc * 64 + nf * 16 + ln15;
        boff[nf] = r * 32 + (lg ^ ((r >> 1) & 3)) * 8;
    }

    f32x4 acc[2][4];
    #pragma unroll
    for (int i = 0; i < 2; ++i)
        #pragma unroll
        for (int j = 0; j < 4; ++j)
            acc[i][j] = (f32x4){0.f, 0.f, 0.f, 0.f};

    // ---- prologue: stage tile 0 into buf 0 ----
    {
        const float4 lo = *(const float4*)(gA);
        const float4 hi = *(const float4*)(gA + 4);
        bf16x8 ab;
        ab[0] = (__bf16)lo.x; ab[1] = (__bf16)lo.y;
        ab[2] = (__bf16)lo.z; ab[3] = (__bf16)lo.w;
        ab[4] = (__bf16)hi.x; ab[5] = (__bf16)hi.y;
        ab[6] = (__bf16)hi.z; ab[7] = (__bf16)hi.w;
        *(bf16x8*)&Ash[0][awr] = ab;
        gl_lds16(gB, &Bsh[0][t * 8]);
    }
    __syncthreads();

    const int nt = Kd / 32;
    int cur = 0;
    for (int kt = 0; kt < nt; ++kt) {
        float4 alo, ahi;
        const bool more = (kt + 1 < nt);
        if (more) {
            const int ko = (kt + 1) * 32;
            alo = *(const float4*)(gA + ko);       // issue early: fly under MFMA
            ahi = *(const float4*)(gA + ko + 4);
            gl_lds16(gB + ko, &Bsh[cur ^ 1][t * 8]);
        }

        bf16x8 fa[2], fb[4];
        #pragma unroll
        for (int mf = 0; mf < 2; ++mf)
            fa[mf] = *(const bf16x8*)&Ash[cur][aoff[mf]];
        #pragma unroll
        for (int nf = 0; nf < 4; ++nf)
            fb[nf] = *(const bf16x8*)&Bsh[cur][boff[nf]];
        #pragma unroll
        for (int mf = 0; mf < 2; ++mf)
            #pragma unroll
            for (int nf = 0; nf < 4; ++nf)
                acc[mf][nf] = __builtin_amdgcn_mfma_f32_16x16x32_bf16(
                    fa[mf], fb[nf], acc[mf][nf], 0, 0, 0);

        if (more) {
            bf16x8 ab;
            ab[0] = (__bf16)alo.x; ab[1] = (__bf16)alo.y;
            ab[2] = (__bf16)alo.z; ab[3] = (__bf16)alo.w;
            ab[4] = (__bf16)ahi.x; ab[5] = (__bf16)ahi.y;
            ab[6] = (__bf16)ahi.z; ab[7] = (__bf16)ahi.w;
            *(bf16x8*)&Ash[cur ^ 1][awr] = ab;
        }
        __syncthreads();   // drains vmcnt (B) + lgkm (A write): next buf ready
        cur ^= 1;
    }

    // ---- epilogue: per-row sum of gelu(c + b1)*W2 over this wave's 64 cols ----
    float b1v[4], w2v[4];
    #pragma unroll
    for (int nf = 0; nf < 4; ++nf) {
        const int n = n0 + wc * 64 + nf * 16 + ln15;
        b1v[nf] = b1[n];
        w2v[nf] = W2[n];
    }
    #pragma unroll
    for (int mf = 0; mf < 2; ++mf)
        #pragma unroll
        for (int j = 0; j < 4; ++j) {
            float s = 0.f;
            #pragma unroll
            for (int nf = 0; nf < 4; ++nf) {
                float c = acc[mf][nf][j] + b1v[nf];
                s += gelu_f(c) * w2v[nf];
            }
            s += __shfl_xor(s, 1);
            s += __shfl_xor(s, 2);
            s += __shfl_xor(s, 4);
            s += __shfl_xor(s, 8);
            if (ln15 == 0) {
                const int m = m0 + wr * 32 + mf * 16 + lg * 4 + j;
                partial[(size_t)m * NT2 + blockIdx.y * 2 + wc] = s;
            }
        }
}

// ---------------------------------------------------------------------------
// K2a: M-parallel logits + probs. One thread per position; 12 contiguous
// partial loads. 64 blocks -> latency covered by TLP.
// ---------------------------------------------------------------------------
__global__ __launch_bounds__(256) void k2a_logits(
    const float* __restrict__ partial, const float* __restrict__ lengths,
    const float* __restrict__ b2p, float* __restrict__ logits,
    float* __restrict__ out_probs, int S)
{
    const int idx = blockIdx.x * 256 + threadIdx.x;
    const int b = idx / S, s = idx - b * S;
    float sum = b2p[0];
    #pragma unroll
    for (int jt = 0; jt < NT2; ++jt)
        sum += partial[(size_t)idx * NT2 + jt];
    logits[idx] = sum;
    const int len = (int)(lengths[b] * (float)S);
    out_probs[idx] = (s < len) ? 1.0f / (1.0f + expf(-sum)) : 0.0f;
}

// ---------------------------------------------------------------------------
// K2b: per-batch flags (logit>0, last_valid=1); scan -> bpos; nb/short/lens.
// ---------------------------------------------------------------------------
__global__ __launch_bounds__(256) void k2b_scan(
    const float* __restrict__ logits, const float* __restrict__ lengths,
    float* __restrict__ out_short, float* __restrict__ out_nb,
    float* __restrict__ out_lens, int* __restrict__ bpos,
    int* __restrict__ nb_arr, int S, int K)
{
    const int b = blockIdx.x;
    const int t = threadIdx.x;
    const int len = (int)(lengths[b] * (float)S);

    __shared__ int cnt[256];
    __shared__ int flags_s[2048];

    const int RP = S / 256;
    const int base_s = t * RP;
    int local = 0;
    #pragma unroll
    for (int r = 0; r < 8; ++r) {
        int s = base_s + r;
        bool v = (s < len);
        int f = (s == len - 1) ? 1 : ((v && logits[(size_t)b * S + s] > 0.0f) ? 1 : 0);
        flags_s[s] = f;
        local += f;
    }
    cnt[t] = local;
    __syncthreads();
    for (int off = 1; off < 256; off <<= 1) {
        int v = cnt[t];
        int u = (t >= off) ? cnt[t - off] : 0;
        __syncthreads();
        cnt[t] = v + u;
        __syncthreads();
    }
    int excl = cnt[t] - local;
    int total = cnt[255];
    for (int r = 0; r < RP; ++r) {
        int s = base_s + r;
        if (flags_s[s]) { bpos[b * S + excl] = s; ++excl; }
    }
    if (t == 0) {
        nb_arr[b] = total;
        float nbf = (float)total;
        float Kf  = (float)K;
        out_nb[b]   = nbf;
        out_lens[b] = (float)len;
        float sh;
        if (nbf >= Kf - 1.0f)      sh = 1.0f;
        else if (nbf > 0.0f)       sh = (nbf + 1.0f) / Kf;
        else                       sh = 0.0f;
        out_short[b] = sh;
    }
}

// ---------------------------------------------------------------------------
// K3: segment-mean pooling from fp32 X. One block per (b,k).
// ---------------------------------------------------------------------------
__global__ __launch_bounds__(192) void k3_pool(
    const float* __restrict__ X, const int* __restrict__ bpos,
    const int* __restrict__ nb_arr, float* __restrict__ pooled,
    int S, int D, int K)
{
    const int bk = blockIdx.x;
    const int b  = bk / K;
    const int k  = bk - b * K;
    const int t  = threadIdx.x;
    const int nb = nb_arr[b];

    float4 acc = {0.f, 0.f, 0.f, 0.f};
    if (k < nb) {
        int start = (k == 0) ? 0 : (bpos[b * S + k - 1] + 1);
        int end   = bpos[b * S + k] + 1;
        float cntf = (float)(end - start);
        for (int s = start; s < end; ++s) {
            const float4 v = *(const float4*)&X[((size_t)b * S + s) * D + t * 4];
            acc.x += v.x; acc.y += v.y; acc.z += v.z; acc.w += v.w;
        }
        acc.x /= cntf; acc.y /= cntf; acc.z /= cntf; acc.w /= cntf;
    }
    *(float4*)&pooled[((size_t)b * K + k) * D + t * 4] = acc;
}

// ---------------------------------------------------------------------------
extern "C" void kernel_launch(void* const* d_in, const int* in_sizes, int n_in,
                              void* d_out, int out_size, void* d_ws, size_t ws_size,
                              hipStream_t stream) {
    const float* hidden  = (const float*)d_in[0];
    const float* lengths = (const float*)d_in[1];
    const float* W1      = (const float*)d_in[2];
    const float* b1      = (const float*)d_in[3];
    const float* W2      = (const float*)d_in[4];
    const float* b2      = (const float*)d_in[5];

    const int B = in_sizes[1];
    const int D = in_sizes[3];
    const int S = in_sizes[0] / (B * D);
    const int M = B * S;
    const int K = (out_size - B * S - 3 * B) / (B * D);

    float* out_pooled = (float*)d_out;
    float* out_probs  = out_pooled + (size_t)B * K * D;
    float* out_short  = out_probs + (size_t)B * S;
    float* out_nb     = out_short + B;
    float* out_lens   = out_nb + B;

    // d_ws: partial (786 KB) + logits (64 KB) + bpos (64 KB) + nb_arr
    char* wsp = (char*)d_ws;
    float* partial = (float*)wsp; wsp += (size_t)M * NT2 * sizeof(float);
    float* logits  = (float*)wsp; wsp += (size_t)M * sizeof(float);
    int*   bpos    = (int*)wsp;   wsp += (size_t)M * sizeof(int);
    int*   nb_arr  = (int*)wsp;

    // bf16 W1^T lives in the pooled output region (K3 overwrites it at the end).
    __bf16* W1t = (__bf16*)out_pooled;

    dim3 gs(D / 32, D / 32);
    s0_w1t<<<gs, 256, 0, stream>>>(W1, W1t, D);

    dim3 g1(M / 128, D / 128);
    k1_hyb<<<g1, 512, 0, stream>>>(hidden, W1t, b1, W2, partial, D);

    k2a_logits<<<M / 256, 256, 0, stream>>>(partial, lengths, b2, logits,
                                            out_probs, S);
    k2b_scan<<<B, 256, 0, stream>>>(logits, lengths, out_short, out_nb,
                                    out_lens, bpos, nb_arr, S, K);
    k3_pool<<<B * K, D / 4, 0, stream>>>(hidden, bpos, nb_arr, out_pooled, S, D, K);
}